// Round 3
// baseline (2789.885 us; speedup 1.0000x reference)
//
#include <hip/hip_runtime.h>

// GRU B=256 T=512 I=128 H=256 + MLP head. fp16 MFMA (swapped operands: D = W·h^T),
// fp32 accumulate, register-resident weights, raw barriers (no vmcnt drain), P prefetch.
// v3: Z-gate moved to phase B with reg-resident h-fragments; 2x t-unroll; setprio.
//
// ws layout (bytes):
//   [0)        Wp  : fp16 recurrent weights row-major  Whr|Whz|Wh  (3*256*256*2 = 393216)
//   [393216)   Wxp : fp16 input weights row-major Wxr|Wxz|Wxn      (3*256*128*2 = 196608)
//   [589824)   h_state : fp32 [256][256]                            (262144)
//   [851968)   P   : fp16 projections, chunked over T
//              per t: [16 btile][16 ntile][3 gate][64 lane][4] shorts = 393216 B
//              value at (ntile,gate,lane,j): pre[n = ntile*16 + 4*(lane>>4) + j][b = lane&15]

typedef _Float16 half8 __attribute__((ext_vector_type(8)));
typedef float    f32x4 __attribute__((ext_vector_type(4)));

#define BARRIER() asm volatile("s_waitcnt lgkmcnt(0)\n\ts_barrier" ::: "memory")

__device__ __forceinline__ unsigned short f2s(float f) {
    _Float16 h = (_Float16)f; unsigned short s; __builtin_memcpy(&s, &h, 2); return s;
}
__device__ __forceinline__ float s2f(unsigned short s) {
    _Float16 h; __builtin_memcpy(&h, &s, 2); return (float)h;
}
__device__ __forceinline__ float fast_sigmoid(float x) {
    return __builtin_amdgcn_rcpf(1.0f + __builtin_amdgcn_exp2f(-1.4426950408889634f * x));
}
__device__ __forceinline__ float fast_tanh(float x) {
    return 1.0f - 2.0f * __builtin_amdgcn_rcpf(1.0f + __builtin_amdgcn_exp2f(2.885390081777927f * x));
}
__device__ __forceinline__ unsigned int pk2(float lo, float hi) {
    return (unsigned int)f2s(lo) | ((unsigned int)f2s(hi) << 16);
}
__device__ __forceinline__ f32x4 up4(uint2 u) {
    return (f32x4){ s2f((unsigned short)u.x), s2f((unsigned short)(u.x >> 16)),
                    s2f((unsigned short)u.y), s2f((unsigned short)(u.y >> 16)) };
}
union H8U4 { half8 h; uint4 u; };
__device__ __forceinline__ half8 ldg_h8(const unsigned short* p) {
    H8U4 t; t.u = *reinterpret_cast<const uint4*>(p); return t.h;
}
__device__ __forceinline__ half8 pack8(float4 a, float4 b) {
    half8 r;
    r[0] = (_Float16)a.x; r[1] = (_Float16)a.y; r[2] = (_Float16)a.z; r[3] = (_Float16)a.w;
    r[4] = (_Float16)b.x; r[5] = (_Float16)b.y; r[6] = (_Float16)b.z; r[7] = (_Float16)b.w;
    return r;
}

// ---------------- pack weights to fp16 ----------------
__global__ void pack_w_kernel(const float* __restrict__ whr, const float* __restrict__ whz,
                              const float* __restrict__ wh,  const float* __restrict__ wxr,
                              const float* __restrict__ wxz, const float* __restrict__ wxn,
                              unsigned short* __restrict__ Wall) {
    const int i = blockIdx.x * 256 + threadIdx.x;  // 0 .. 294911
    float v;
    if (i < 196608) {
        const int m = i >> 16;
        const int r = i & 65535;
        v = (m == 0 ? whr : (m == 1 ? whz : wh))[r];
    } else {
        const int ii = i - 196608;
        const int m = ii >> 15;
        const int r = ii & 32767;
        v = (m == 0 ? wxr : (m == 1 ? wxz : wxn))[r];
    }
    Wall[i] = f2s(v);
}

// ---------------- input projections (MFMA, swapped: D = Wx . x^T) ----------------
__global__ __launch_bounds__(256) void proj_kernel(
    const float* __restrict__ x, const unsigned short* __restrict__ Wxp,
    const float* __restrict__ br, const float* __restrict__ bz, const float* __restrict__ bn,
    unsigned short* __restrict__ P, int t0) {
    const int tid = threadIdx.x;
    const int wv  = tid >> 6;
    const int lane = tid & 63;
    const int l15 = lane & 15;
    const int lq  = lane >> 4;
    const int tl = blockIdx.x >> 4;
    const int btile = blockIdx.x & 15;
    const int t = t0 + tl;
    const int b0 = btile * 16;

    half8 xf[4];
#pragma unroll
    for (int kt = 0; kt < 4; ++kt) {
        const float* xp = x + (size_t)(b0 + l15) * 65536 + t * 128 + kt * 32 + 8 * lq;
        float4 f0 = *reinterpret_cast<const float4*>(xp);
        float4 f1 = *reinterpret_cast<const float4*>(xp + 4);
        xf[kt] = pack8(f0, f1);
    }
    const float* bptr[3] = {br, bz, bn};
    unsigned short* Pb = P + (size_t)tl * 196608 + btile * 12288;
#pragma unroll
    for (int g = 0; g < 3; ++g) {
#pragma unroll
        for (int ntl = 0; ntl < 4; ++ntl) {
            const int nt = wv * 4 + ntl;
            const int n0 = nt * 16;
            f32x4 acc = {0.f, 0.f, 0.f, 0.f};
#pragma unroll
            for (int kt = 0; kt < 4; ++kt) {
                half8 wf = ldg_h8(Wxp + g * 32768 + (n0 + l15) * 128 + kt * 32 + 8 * lq);
                acc = __builtin_amdgcn_mfma_f32_16x16x32_f16(wf, xf[kt], acc, 0, 0, 0);
            }
            float4 bv = *reinterpret_cast<const float4*>(bptr[g] + n0 + 4 * lq);
            uint2 o;
            o.x = pk2(acc[0] + bv.x, acc[1] + bv.y);
            o.y = pk2(acc[2] + bv.z, acc[3] + bv.w);
            *reinterpret_cast<uint2*>(Pb + nt * 768 + g * 256 + lane * 4) = o;
        }
    }
}

// ---------------- recurrent scan (persistent, weights in registers) ----------------
__global__ __launch_bounds__(512, 1) void rec_kernel(
    const unsigned short* __restrict__ Wp, const unsigned short* __restrict__ P,
    float* __restrict__ h_state, int t0, int Tc) {
    const int tid = threadIdx.x;
    const int w = tid >> 6;       // wave 0..7, owns n-cols w*32 .. w*32+31 of each gate
    const int lane = tid & 63;
    const int l15 = lane & 15;    // batch row within tile (and weight n-row for A-frags)
    const int lq = lane >> 4;
    const int btile = blockIdx.x;
    const int b0 = btile * 16;

    // bytes [0,8192): h  (16 rows x 256 n fp16, chunk-XOR swizzled); [8192,16384): rh
    __shared__ __align__(16) unsigned short hl[8192];
    char* lds = reinterpret_cast<char*>(hl);

    // A-fragments of weights: lane l15 = n-row (within 16-tile), k = kt*32 + 8*lq
    half8 wr[8][2], wz[8][2], wn[8][2];
#pragma unroll
    for (int kt = 0; kt < 8; ++kt) {
#pragma unroll
        for (int nt = 0; nt < 2; ++nt) {
            const int row = w * 32 + nt * 16 + l15;
            const int co = kt * 32 + 8 * lq;
            wr[kt][nt] = ldg_h8(Wp + row * 256 + co);
            wz[kt][nt] = ldg_h8(Wp + 65536 + row * 256 + co);
            wn[kt][nt] = ldg_h8(Wp + 131072 + row * 256 + co);
        }
    }

    // loop-invariant LDS addresses (bytes). Row b (512 B) x 32 chunks of 16 B,
    // physical chunk = logical chunk ^ (b & 7).
    const int b7 = l15 & 7;
    int rdaddr[8];
#pragma unroll
    for (int kt = 0; kt < 8; ++kt)
        rdaddr[kt] = l15 * 512 + (((4 * kt + lq) ^ b7) << 4);
    int waddr[2];
#pragma unroll
    for (int nt = 0; nt < 2; ++nt) {
        const int c = 4 * w + 2 * nt + (lq >> 1);
        waddr[nt] = l15 * 512 + ((c ^ b7) << 4) + 8 * (lq & 1);
    }

    // h register state: hreg[nt][j] = h[b = l15][n = w*32 + nt*16 + 4*lq + j]
    float hreg[2][4];
    if (t0 == 0) {
#pragma unroll
        for (int nt = 0; nt < 2; ++nt)
#pragma unroll
            for (int j = 0; j < 4; ++j) hreg[nt][j] = 0.f;
    } else {
#pragma unroll
        for (int nt = 0; nt < 2; ++nt) {
            float4 v = *reinterpret_cast<const float4*>(
                h_state + (b0 + l15) * 256 + w * 32 + nt * 16 + 4 * lq);
            hreg[nt][0] = v.x; hreg[nt][1] = v.y; hreg[nt][2] = v.z; hreg[nt][3] = v.w;
        }
    }
#pragma unroll
    for (int nt = 0; nt < 2; ++nt) {
        uint2 o;
        o.x = pk2(hreg[nt][0], hreg[nt][1]);
        o.y = pk2(hreg[nt][2], hreg[nt][3]);
        *reinterpret_cast<uint2*>(lds + waddr[nt]) = o;
    }
    BARRIER();

    const unsigned short* Pw = P + btile * 12288 + (2 * w) * 768 + lane * 4;
    uint2 cpA[3][2], cpB[3][2];
#pragma unroll
    for (int g = 0; g < 3; ++g)
#pragma unroll
        for (int nt = 0; nt < 2; ++nt)
            cpA[g][nt] = *reinterpret_cast<const uint2*>(Pw + nt * 768 + g * 256);

    auto STEP = [&](uint2 (&cp)[3][2], uint2 (&np)[3][2], const unsigned short* Pn) {
        // prefetch next step's P (stays in flight across raw barriers)
#pragma unroll
        for (int g = 0; g < 3; ++g)
#pragma unroll
            for (int nt = 0; nt < 2; ++nt)
                np[g][nt] = *reinterpret_cast<const uint2*>(Pn + nt * 768 + g * 256);

        // ---- phase A: read full h into regs, R gate only ----
        half8 hf[8];
#pragma unroll
        for (int kt = 0; kt < 8; ++kt)
            hf[kt] = *reinterpret_cast<const half8*>(lds + rdaddr[kt]);
        f32x4 aR[2];
        aR[0] = up4(cp[0][0]);
        aR[1] = up4(cp[0][1]);
        __builtin_amdgcn_s_setprio(1);
#pragma unroll
        for (int kt = 0; kt < 8; ++kt) {
            aR[0] = __builtin_amdgcn_mfma_f32_16x16x32_f16(wr[kt][0], hf[kt], aR[0], 0, 0, 0);
            aR[1] = __builtin_amdgcn_mfma_f32_16x16x32_f16(wr[kt][1], hf[kt], aR[1], 0, 0, 0);
        }
        __builtin_amdgcn_s_setprio(0);
#pragma unroll
        for (int nt = 0; nt < 2; ++nt) {
            const float r0 = fast_sigmoid(aR[nt][0]);
            const float r1 = fast_sigmoid(aR[nt][1]);
            const float r2 = fast_sigmoid(aR[nt][2]);
            const float r3 = fast_sigmoid(aR[nt][3]);
            uint2 o;
            o.x = pk2(r0 * hreg[nt][0], r1 * hreg[nt][1]);
            o.y = pk2(r2 * hreg[nt][2], r3 * hreg[nt][3]);
            *reinterpret_cast<uint2*>(lds + 8192 + waddr[nt]) = o;
        }
        BARRIER();

        // ---- phase B: Z gate from reg-resident hf (no LDS wait) + N gate from rh ----
        half8 rf[8];
#pragma unroll
        for (int kt = 0; kt < 8; ++kt)
            rf[kt] = *reinterpret_cast<const half8*>(lds + 8192 + rdaddr[kt]);
        f32x4 aZ[2], aN[2];
        aZ[0] = up4(cp[1][0]);
        aZ[1] = up4(cp[1][1]);
        aN[0] = up4(cp[2][0]);
        aN[1] = up4(cp[2][1]);
        __builtin_amdgcn_s_setprio(1);
#pragma unroll
        for (int kt = 0; kt < 8; ++kt) {
            aZ[0] = __builtin_amdgcn_mfma_f32_16x16x32_f16(wz[kt][0], hf[kt], aZ[0], 0, 0, 0);
            aZ[1] = __builtin_amdgcn_mfma_f32_16x16x32_f16(wz[kt][1], hf[kt], aZ[1], 0, 0, 0);
        }
#pragma unroll
        for (int kt = 0; kt < 8; ++kt) {
            aN[0] = __builtin_amdgcn_mfma_f32_16x16x32_f16(wn[kt][0], rf[kt], aN[0], 0, 0, 0);
            aN[1] = __builtin_amdgcn_mfma_f32_16x16x32_f16(wn[kt][1], rf[kt], aN[1], 0, 0, 0);
        }
        __builtin_amdgcn_s_setprio(0);
#pragma unroll
        for (int nt = 0; nt < 2; ++nt) {
            const float z0 = fast_sigmoid(aZ[nt][0]);
            const float z1 = fast_sigmoid(aZ[nt][1]);
            const float z2 = fast_sigmoid(aZ[nt][2]);
            const float z3 = fast_sigmoid(aZ[nt][3]);
            const float t0_ = fast_tanh(aN[nt][0]);
            const float t1_ = fast_tanh(aN[nt][1]);
            const float t2_ = fast_tanh(aN[nt][2]);
            const float t3_ = fast_tanh(aN[nt][3]);
            hreg[nt][0] = t0_ + z0 * (hreg[nt][0] - t0_);
            hreg[nt][1] = t1_ + z1 * (hreg[nt][1] - t1_);
            hreg[nt][2] = t2_ + z2 * (hreg[nt][2] - t2_);
            hreg[nt][3] = t3_ + z3 * (hreg[nt][3] - t3_);
            uint2 o;
            o.x = pk2(hreg[nt][0], hreg[nt][1]);
            o.y = pk2(hreg[nt][2], hreg[nt][3]);
            *reinterpret_cast<uint2*>(lds + waddr[nt]) = o;
        }
        BARRIER();
    };

    for (int tl = 0; tl < Tc; tl += 2) {
        const unsigned short* Pn1 = Pw + (size_t)((tl + 1 < Tc) ? tl + 1 : Tc - 1) * 196608;
        STEP(cpA, cpB, Pn1);
        if (tl + 1 < Tc) {
            const unsigned short* Pn2 = Pw + (size_t)((tl + 2 < Tc) ? tl + 2 : Tc - 1) * 196608;
            STEP(cpB, cpA, Pn2);
        }
    }

#pragma unroll
    for (int nt = 0; nt < 2; ++nt) {
        float4 st;
        st.x = hreg[nt][0]; st.y = hreg[nt][1]; st.z = hreg[nt][2]; st.w = hreg[nt][3];
        *reinterpret_cast<float4*>(h_state + (b0 + l15) * 256 + w * 32 + nt * 16 + 4 * lq) = st;
    }
}

// ---------------- MLP head + softmax ----------------
__global__ __launch_bounds__(64) void head_kernel(
    const float* __restrict__ h_state, const float* __restrict__ w1, const float* __restrict__ b1,
    const float* __restrict__ w2, const float* __restrict__ b2, float* __restrict__ out) {
    const int row = blockIdx.x;
    const int lane = threadIdx.x;
    __shared__ float hs[256];
    __shared__ float h2[64];
    __shared__ float lg[10];
    float4 v = *reinterpret_cast<const float4*>(h_state + row * 256 + lane * 4);
    hs[lane * 4 + 0] = fast_sigmoid(v.x);
    hs[lane * 4 + 1] = fast_sigmoid(v.y);
    hs[lane * 4 + 2] = fast_sigmoid(v.z);
    hs[lane * 4 + 3] = fast_sigmoid(v.w);
    __syncthreads();
    float acc = b1[lane];
#pragma unroll 4
    for (int k = 0; k < 256; k += 4) {
        float4 wv = *reinterpret_cast<const float4*>(w1 + lane * 256 + k);
        acc += hs[k] * wv.x + hs[k + 1] * wv.y + hs[k + 2] * wv.z + hs[k + 3] * wv.w;
    }
    h2[lane] = fast_sigmoid(acc);
    __syncthreads();
    if (lane < 10) {
        float a2 = b2[lane];
        for (int k = 0; k < 64; ++k) a2 += h2[k] * w2[lane * 64 + k];
        lg[lane] = a2;
    }
    __syncthreads();
    if (lane < 10) {
        float m = lg[0];
#pragma unroll
        for (int k = 1; k < 10; ++k) m = fmaxf(m, lg[k]);
        float s = 0.f;
#pragma unroll
        for (int k = 0; k < 10; ++k) s += __expf(lg[k] - m);
        out[row * 10 + lane] = __expf(lg[lane] - m) / s;
    }
}

extern "C" void kernel_launch(void* const* d_in, const int* in_sizes, int n_in,
                              void* d_out, int out_size, void* d_ws, size_t ws_size,
                              hipStream_t stream) {
    const float* x   = (const float*)d_in[0];
    const float* wxr = (const float*)d_in[1];
    const float* whr = (const float*)d_in[2];
    const float* br  = (const float*)d_in[3];
    const float* wxz = (const float*)d_in[4];
    const float* whz = (const float*)d_in[5];
    const float* bz  = (const float*)d_in[6];
    const float* wxn = (const float*)d_in[7];
    const float* wh  = (const float*)d_in[8];
    const float* bn  = (const float*)d_in[9];
    const float* w1  = (const float*)d_in[10];
    const float* b1  = (const float*)d_in[11];
    const float* w2  = (const float*)d_in[12];
    const float* b2  = (const float*)d_in[13];
    float* out = (float*)d_out;

    char* ws = (char*)d_ws;
    unsigned short* Wp  = (unsigned short*)ws;
    unsigned short* Wxp = (unsigned short*)(ws + 393216);
    float* h_state = (float*)(ws + 589824);
    unsigned short* P = (unsigned short*)(ws + 851968);
    const size_t avail = (ws_size > 851968) ? ws_size - 851968 : 0;
    int Tc = 512;
    while (Tc > 1 && (size_t)Tc * 393216 > avail) Tc >>= 1;

    pack_w_kernel<<<dim3(1152), 256, 0, stream>>>(whr, whz, wh, wxr, wxz, wxn, Wp);
    for (int t0 = 0; t0 < 512; t0 += Tc) {
        proj_kernel<<<dim3(Tc * 16), 256, 0, stream>>>(x, Wxp, br, bz, bn, P, t0);
        rec_kernel<<<dim3(16), 512, 0, stream>>>(Wp, P, h_state, t0, Tc);
    }
    head_kernel<<<dim3(256), 64, 0, stream>>>(h_state, w1, b1, w2, b2, out);
}

// Round 4
// 1127.542 us; speedup vs baseline: 2.4743x; 2.4743x over previous
//
#include <hip/hip_runtime.h>

// GRU B=256 T=512 I=128 H=256 + MLP head. fp16 MFMA (swapped operands: D = W·h^T),
// fp32 accumulate, register-resident weights, raw barriers (no vmcnt drain), P prefetch.
// v4: round-2 rec body + setprio + deferred z-sigmoid (reg-neutral) + 2x ping-pong unroll;
//     proj rewritten with register-resident weights, 32 timesteps per block.
//
// ws layout (bytes):
//   [0)        Wp  : fp16 recurrent weights row-major  Whr|Whz|Wh  (3*256*256*2 = 393216)
//   [393216)   Wxp : fp16 input weights row-major Wxr|Wxz|Wxn      (3*256*128*2 = 196608)
//   [589824)   h_state : fp32 [256][256]                            (262144)
//   [851968)   P   : fp16 projections, chunked over T
//              per t: [16 btile][16 ntile][3 gate][64 lane][4] shorts = 393216 B
//              value at (ntile,gate,lane,j): pre[n = ntile*16 + 4*(lane>>4) + j][b = lane&15]

typedef _Float16 half8 __attribute__((ext_vector_type(8)));
typedef float    f32x4 __attribute__((ext_vector_type(4)));

#define BARRIER() asm volatile("s_waitcnt lgkmcnt(0)\n\ts_barrier" ::: "memory")

__device__ __forceinline__ unsigned short f2s(float f) {
    _Float16 h = (_Float16)f; unsigned short s; __builtin_memcpy(&s, &h, 2); return s;
}
__device__ __forceinline__ float s2f(unsigned short s) {
    _Float16 h; __builtin_memcpy(&h, &s, 2); return (float)h;
}
__device__ __forceinline__ float fast_sigmoid(float x) {
    return __builtin_amdgcn_rcpf(1.0f + __builtin_amdgcn_exp2f(-1.4426950408889634f * x));
}
__device__ __forceinline__ float fast_tanh(float x) {
    return 1.0f - 2.0f * __builtin_amdgcn_rcpf(1.0f + __builtin_amdgcn_exp2f(2.885390081777927f * x));
}
__device__ __forceinline__ unsigned int pk2(float lo, float hi) {
    return (unsigned int)f2s(lo) | ((unsigned int)f2s(hi) << 16);
}
__device__ __forceinline__ f32x4 up4(uint2 u) {
    return (f32x4){ s2f((unsigned short)u.x), s2f((unsigned short)(u.x >> 16)),
                    s2f((unsigned short)u.y), s2f((unsigned short)(u.y >> 16)) };
}
union H8U4 { half8 h; uint4 u; };
__device__ __forceinline__ half8 ldg_h8(const unsigned short* p) {
    H8U4 t; t.u = *reinterpret_cast<const uint4*>(p); return t.h;
}
__device__ __forceinline__ half8 pack8(float4 a, float4 b) {
    half8 r;
    r[0] = (_Float16)a.x; r[1] = (_Float16)a.y; r[2] = (_Float16)a.z; r[3] = (_Float16)a.w;
    r[4] = (_Float16)b.x; r[5] = (_Float16)b.y; r[6] = (_Float16)b.z; r[7] = (_Float16)b.w;
    return r;
}

// ---------------- pack weights to fp16 ----------------
__global__ void pack_w_kernel(const float* __restrict__ whr, const float* __restrict__ whz,
                              const float* __restrict__ wh,  const float* __restrict__ wxr,
                              const float* __restrict__ wxz, const float* __restrict__ wxn,
                              unsigned short* __restrict__ Wall) {
    const int i = blockIdx.x * 256 + threadIdx.x;  // 0 .. 294911
    float v;
    if (i < 196608) {
        const int m = i >> 16;
        const int r = i & 65535;
        v = (m == 0 ? whr : (m == 1 ? whz : wh))[r];
    } else {
        const int ii = i - 196608;
        const int m = ii >> 15;
        const int r = ii & 32767;
        v = (m == 0 ? wxr : (m == 1 ? wxz : wxn))[r];
    }
    Wall[i] = f2s(v);
}

// ---------------- input projections (weights register-resident, 32 t per block) ----
// grid: 16 btile x (Tc/TPB) tchunks; 512 threads; wave w owns ntiles {2w, 2w+1}.
__global__ __launch_bounds__(512, 1) void proj_kernel(
    const float* __restrict__ x, const unsigned short* __restrict__ Wxp,
    const float* __restrict__ br, const float* __restrict__ bz, const float* __restrict__ bn,
    unsigned short* __restrict__ P, int t0, int TPB) {
    const int tid = threadIdx.x;
    const int w   = tid >> 6;
    const int lane = tid & 63;
    const int l15 = lane & 15;
    const int lq  = lane >> 4;
    const int btile = blockIdx.x & 15;
    const int tc    = blockIdx.x >> 4;
    const int b0 = btile * 16;

    // weight A-fragments: row = w*32 + ntl*16 + l15, k = kt*32 + 8*lq
    half8 wf[3][4][2];
#pragma unroll
    for (int g = 0; g < 3; ++g)
#pragma unroll
        for (int kt = 0; kt < 4; ++kt)
#pragma unroll
            for (int ntl = 0; ntl < 2; ++ntl)
                wf[g][kt][ntl] = ldg_h8(Wxp + g * 32768 + (w * 32 + ntl * 16 + l15) * 128 + kt * 32 + 8 * lq);

    const float* bptr[3] = {br, bz, bn};
    float4 bv[3][2];
#pragma unroll
    for (int g = 0; g < 3; ++g)
#pragma unroll
        for (int ntl = 0; ntl < 2; ++ntl)
            bv[g][ntl] = *reinterpret_cast<const float4*>(bptr[g] + (2 * w + ntl) * 16 + 4 * lq);

    for (int i = 0; i < TPB; ++i) {
        const int tl = tc * TPB + i;           // chunk-relative t
        const int t  = t0 + tl;                // absolute t
        half8 xf[4];
#pragma unroll
        for (int kt = 0; kt < 4; ++kt) {
            const float* xp = x + (size_t)(b0 + l15) * 65536 + t * 128 + kt * 32 + 8 * lq;
            float4 f0 = *reinterpret_cast<const float4*>(xp);
            float4 f1 = *reinterpret_cast<const float4*>(xp + 4);
            xf[kt] = pack8(f0, f1);
        }
        unsigned short* Pb = P + (size_t)tl * 196608 + btile * 12288;
#pragma unroll
        for (int g = 0; g < 3; ++g) {
#pragma unroll
            for (int ntl = 0; ntl < 2; ++ntl) {
                f32x4 acc = {0.f, 0.f, 0.f, 0.f};
#pragma unroll
                for (int kt = 0; kt < 4; ++kt)
                    acc = __builtin_amdgcn_mfma_f32_16x16x32_f16(wf[g][kt][ntl], xf[kt], acc, 0, 0, 0);
                uint2 o;
                o.x = pk2(acc[0] + bv[g][ntl].x, acc[1] + bv[g][ntl].y);
                o.y = pk2(acc[2] + bv[g][ntl].z, acc[3] + bv[g][ntl].w);
                *reinterpret_cast<uint2*>(Pb + (2 * w + ntl) * 768 + g * 256 + lane * 4) = o;
            }
        }
    }
}

// ---------------- recurrent scan (persistent, weights in registers) ----------------
__global__ __launch_bounds__(512, 1) void rec_kernel(
    const unsigned short* __restrict__ Wp, const unsigned short* __restrict__ P,
    float* __restrict__ h_state, int t0, int Tc) {
    const int tid = threadIdx.x;
    const int w = tid >> 6;       // wave 0..7, owns n-cols w*32 .. w*32+31 of each gate
    const int lane = tid & 63;
    const int l15 = lane & 15;    // batch row within tile (and weight n-row for A-frags)
    const int lq = lane >> 4;
    const int btile = blockIdx.x;
    const int b0 = btile * 16;

    // bytes [0,8192): h  (16 rows x 256 n fp16, chunk-XOR swizzled); [8192,16384): rh
    __shared__ __align__(16) unsigned short hl[8192];
    char* lds = reinterpret_cast<char*>(hl);

    // A-fragments of weights: lane l15 = n-row (within 16-tile), k = kt*32 + 8*lq
    half8 wr[8][2], wz[8][2], wn[8][2];
#pragma unroll
    for (int kt = 0; kt < 8; ++kt) {
#pragma unroll
        for (int nt = 0; nt < 2; ++nt) {
            const int row = w * 32 + nt * 16 + l15;
            const int co = kt * 32 + 8 * lq;
            wr[kt][nt] = ldg_h8(Wp + row * 256 + co);
            wz[kt][nt] = ldg_h8(Wp + 65536 + row * 256 + co);
            wn[kt][nt] = ldg_h8(Wp + 131072 + row * 256 + co);
        }
    }

    // loop-invariant LDS addresses (bytes). Row b (512 B) x 32 chunks of 16 B,
    // physical chunk = logical chunk ^ (b & 7).
    const int b7 = l15 & 7;
    int rdaddr[8];
#pragma unroll
    for (int kt = 0; kt < 8; ++kt)
        rdaddr[kt] = l15 * 512 + (((4 * kt + lq) ^ b7) << 4);
    int waddr[2];
#pragma unroll
    for (int nt = 0; nt < 2; ++nt) {
        const int c = 4 * w + 2 * nt + (lq >> 1);
        waddr[nt] = l15 * 512 + ((c ^ b7) << 4) + 8 * (lq & 1);
    }

    // h register state: hreg[nt][j] = h[b = l15][n = w*32 + nt*16 + 4*lq + j]
    float hreg[2][4];
    if (t0 == 0) {
#pragma unroll
        for (int nt = 0; nt < 2; ++nt)
#pragma unroll
            for (int j = 0; j < 4; ++j) hreg[nt][j] = 0.f;
    } else {
#pragma unroll
        for (int nt = 0; nt < 2; ++nt) {
            float4 v = *reinterpret_cast<const float4*>(
                h_state + (b0 + l15) * 256 + w * 32 + nt * 16 + 4 * lq);
            hreg[nt][0] = v.x; hreg[nt][1] = v.y; hreg[nt][2] = v.z; hreg[nt][3] = v.w;
        }
    }
#pragma unroll
    for (int nt = 0; nt < 2; ++nt) {
        uint2 o;
        o.x = pk2(hreg[nt][0], hreg[nt][1]);
        o.y = pk2(hreg[nt][2], hreg[nt][3]);
        *reinterpret_cast<uint2*>(lds + waddr[nt]) = o;
    }
    BARRIER();

    const unsigned short* Pw = P + btile * 12288 + (2 * w) * 768 + lane * 4;
    uint2 cpA[3][2], cpB[3][2];
#pragma unroll
    for (int g = 0; g < 3; ++g)
#pragma unroll
        for (int nt = 0; nt < 2; ++nt)
            cpA[g][nt] = *reinterpret_cast<const uint2*>(Pw + nt * 768 + g * 256);

    auto STEP = [&](uint2 (&cp)[3][2], uint2 (&np)[3][2], const unsigned short* Pn) {
        // prefetch next step's P (stays in flight across raw barriers)
#pragma unroll
        for (int g = 0; g < 3; ++g)
#pragma unroll
            for (int nt = 0; nt < 2; ++nt)
                np[g][nt] = *reinterpret_cast<const uint2*>(Pn + nt * 768 + g * 256);

        // ---- phase A: R and Z MFMAs; only r-sigmoids before the barrier ----
        f32x4 aR[2], aZ[2];
        aR[0] = up4(cp[0][0]);
        aR[1] = up4(cp[0][1]);
        aZ[0] = up4(cp[1][0]);
        aZ[1] = up4(cp[1][1]);
        __builtin_amdgcn_s_setprio(1);
#pragma unroll
        for (int kt = 0; kt < 8; ++kt) {
            half8 a = *reinterpret_cast<const half8*>(lds + rdaddr[kt]);
            aR[0] = __builtin_amdgcn_mfma_f32_16x16x32_f16(wr[kt][0], a, aR[0], 0, 0, 0);
            aZ[0] = __builtin_amdgcn_mfma_f32_16x16x32_f16(wz[kt][0], a, aZ[0], 0, 0, 0);
            aR[1] = __builtin_amdgcn_mfma_f32_16x16x32_f16(wr[kt][1], a, aR[1], 0, 0, 0);
            aZ[1] = __builtin_amdgcn_mfma_f32_16x16x32_f16(wz[kt][1], a, aZ[1], 0, 0, 0);
        }
        __builtin_amdgcn_s_setprio(0);
#pragma unroll
        for (int nt = 0; nt < 2; ++nt) {
            const float r0 = fast_sigmoid(aR[nt][0]);
            const float r1 = fast_sigmoid(aR[nt][1]);
            const float r2 = fast_sigmoid(aR[nt][2]);
            const float r3 = fast_sigmoid(aR[nt][3]);
            uint2 o;
            o.x = pk2(r0 * hreg[nt][0], r1 * hreg[nt][1]);
            o.y = pk2(r2 * hreg[nt][2], r3 * hreg[nt][3]);
            *reinterpret_cast<uint2*>(lds + 8192 + waddr[nt]) = o;
        }
        BARRIER();

        // ---- phase B: N gate; z-sigmoids (from live aZ) hide under the MFMAs ----
        f32x4 aN[2];
        aN[0] = up4(cp[2][0]);
        aN[1] = up4(cp[2][1]);
        __builtin_amdgcn_s_setprio(1);
#pragma unroll
        for (int kt = 0; kt < 8; ++kt) {
            half8 rf = *reinterpret_cast<const half8*>(lds + 8192 + rdaddr[kt]);
            aN[0] = __builtin_amdgcn_mfma_f32_16x16x32_f16(wn[kt][0], rf, aN[0], 0, 0, 0);
            aN[1] = __builtin_amdgcn_mfma_f32_16x16x32_f16(wn[kt][1], rf, aN[1], 0, 0, 0);
        }
        __builtin_amdgcn_s_setprio(0);
#pragma unroll
        for (int nt = 0; nt < 2; ++nt) {
            const float z0 = fast_sigmoid(aZ[nt][0]);
            const float z1 = fast_sigmoid(aZ[nt][1]);
            const float z2 = fast_sigmoid(aZ[nt][2]);
            const float z3 = fast_sigmoid(aZ[nt][3]);
            const float t0_ = fast_tanh(aN[nt][0]);
            const float t1_ = fast_tanh(aN[nt][1]);
            const float t2_ = fast_tanh(aN[nt][2]);
            const float t3_ = fast_tanh(aN[nt][3]);
            hreg[nt][0] = t0_ + z0 * (hreg[nt][0] - t0_);
            hreg[nt][1] = t1_ + z1 * (hreg[nt][1] - t1_);
            hreg[nt][2] = t2_ + z2 * (hreg[nt][2] - t2_);
            hreg[nt][3] = t3_ + z3 * (hreg[nt][3] - t3_);
            uint2 o;
            o.x = pk2(hreg[nt][0], hreg[nt][1]);
            o.y = pk2(hreg[nt][2], hreg[nt][3]);
            *reinterpret_cast<uint2*>(lds + waddr[nt]) = o;
        }
        BARRIER();
    };

    for (int tl = 0; tl < Tc; tl += 2) {
        const unsigned short* Pn1 = Pw + (size_t)((tl + 1 < Tc) ? tl + 1 : Tc - 1) * 196608;
        STEP(cpA, cpB, Pn1);
        if (tl + 1 < Tc) {
            const unsigned short* Pn2 = Pw + (size_t)((tl + 2 < Tc) ? tl + 2 : Tc - 1) * 196608;
            STEP(cpB, cpA, Pn2);
        }
    }

#pragma unroll
    for (int nt = 0; nt < 2; ++nt) {
        float4 st;
        st.x = hreg[nt][0]; st.y = hreg[nt][1]; st.z = hreg[nt][2]; st.w = hreg[nt][3];
        *reinterpret_cast<float4*>(h_state + (b0 + l15) * 256 + w * 32 + nt * 16 + 4 * lq) = st;
    }
}

// ---------------- MLP head + softmax ----------------
__global__ __launch_bounds__(64) void head_kernel(
    const float* __restrict__ h_state, const float* __restrict__ w1, const float* __restrict__ b1,
    const float* __restrict__ w2, const float* __restrict__ b2, float* __restrict__ out) {
    const int row = blockIdx.x;
    const int lane = threadIdx.x;
    __shared__ float hs[256];
    __shared__ float h2[64];
    __shared__ float lg[10];
    float4 v = *reinterpret_cast<const float4*>(h_state + row * 256 + lane * 4);
    hs[lane * 4 + 0] = fast_sigmoid(v.x);
    hs[lane * 4 + 1] = fast_sigmoid(v.y);
    hs[lane * 4 + 2] = fast_sigmoid(v.z);
    hs[lane * 4 + 3] = fast_sigmoid(v.w);
    __syncthreads();
    float acc = b1[lane];
#pragma unroll 4
    for (int k = 0; k < 256; k += 4) {
        float4 wv = *reinterpret_cast<const float4*>(w1 + lane * 256 + k);
        acc += hs[k] * wv.x + hs[k + 1] * wv.y + hs[k + 2] * wv.z + hs[k + 3] * wv.w;
    }
    h2[lane] = fast_sigmoid(acc);
    __syncthreads();
    if (lane < 10) {
        float a2 = b2[lane];
        for (int k = 0; k < 64; ++k) a2 += h2[k] * w2[lane * 64 + k];
        lg[lane] = a2;
    }
    __syncthreads();
    if (lane < 10) {
        float m = lg[0];
#pragma unroll
        for (int k = 1; k < 10; ++k) m = fmaxf(m, lg[k]);
        float s = 0.f;
#pragma unroll
        for (int k = 0; k < 10; ++k) s += __expf(lg[k] - m);
        out[row * 10 + lane] = __expf(lg[lane] - m) / s;
    }
}

extern "C" void kernel_launch(void* const* d_in, const int* in_sizes, int n_in,
                              void* d_out, int out_size, void* d_ws, size_t ws_size,
                              hipStream_t stream) {
    const float* x   = (const float*)d_in[0];
    const float* wxr = (const float*)d_in[1];
    const float* whr = (const float*)d_in[2];
    const float* br  = (const float*)d_in[3];
    const float* wxz = (const float*)d_in[4];
    const float* whz = (const float*)d_in[5];
    const float* bz  = (const float*)d_in[6];
    const float* wxn = (const float*)d_in[7];
    const float* wh  = (const float*)d_in[8];
    const float* bn  = (const float*)d_in[9];
    const float* w1  = (const float*)d_in[10];
    const float* b1  = (const float*)d_in[11];
    const float* w2  = (const float*)d_in[12];
    const float* b2  = (const float*)d_in[13];
    float* out = (float*)d_out;

    char* ws = (char*)d_ws;
    unsigned short* Wp  = (unsigned short*)ws;
    unsigned short* Wxp = (unsigned short*)(ws + 393216);
    float* h_state = (float*)(ws + 589824);
    unsigned short* P = (unsigned short*)(ws + 851968);
    const size_t avail = (ws_size > 851968) ? ws_size - 851968 : 0;
    int Tc = 512;
    while (Tc > 1 && (size_t)Tc * 393216 > avail) Tc >>= 1;
    const int TPB = Tc < 32 ? Tc : 32;

    pack_w_kernel<<<dim3(1152), 256, 0, stream>>>(whr, whz, wh, wxr, wxz, wxn, Wp);
    for (int t0 = 0; t0 < 512; t0 += Tc) {
        proj_kernel<<<dim3(16 * (Tc / TPB)), 512, 0, stream>>>(x, Wxp, br, bz, bn, P, t0, TPB);
        rec_kernel<<<dim3(16), 512, 0, stream>>>(Wp, P, h_state, t0, Tc);
    }
    head_kernel<<<dim3(256), 64, 0, stream>>>(h_state, w1, b1, w2, b2, out);
}

// Round 5
// 910.741 us; speedup vs baseline: 3.0633x; 1.2380x over previous
//
#include <hip/hip_runtime.h>

// GRU B=256 T=512 I=128 H=256 + MLP head. fp16 MFMA (swapped operands: D = W·h^T),
// fp32 accumulate, register-resident weights, raw barriers (no vmcnt drain), P prefetch.
// v5: rec = round-2 structure (no setprio, no unroll) + deferred z-sigmoid:
//     phase A epilogue = r-sig only; phase B opens with z-sig (hides under rh ds_reads).
//     proj = v4 register-resident-weight version (confirmed win).
//
// ws layout (bytes):
//   [0)        Wp  : fp16 recurrent weights row-major  Whr|Whz|Wh  (3*256*256*2 = 393216)
//   [393216)   Wxp : fp16 input weights row-major Wxr|Wxz|Wxn      (3*256*128*2 = 196608)
//   [589824)   h_state : fp32 [256][256]                            (262144)
//   [851968)   P   : fp16 projections, chunked over T
//              per t: [16 btile][16 ntile][3 gate][64 lane][4] shorts = 393216 B
//              value at (ntile,gate,lane,j): pre[n = ntile*16 + 4*(lane>>4) + j][b = lane&15]

typedef _Float16 half8 __attribute__((ext_vector_type(8)));
typedef float    f32x4 __attribute__((ext_vector_type(4)));

#define BARRIER() asm volatile("s_waitcnt lgkmcnt(0)\n\ts_barrier" ::: "memory")

__device__ __forceinline__ unsigned short f2s(float f) {
    _Float16 h = (_Float16)f; unsigned short s; __builtin_memcpy(&s, &h, 2); return s;
}
__device__ __forceinline__ float s2f(unsigned short s) {
    _Float16 h; __builtin_memcpy(&h, &s, 2); return (float)h;
}
__device__ __forceinline__ float fast_sigmoid(float x) {
    return __builtin_amdgcn_rcpf(1.0f + __builtin_amdgcn_exp2f(-1.4426950408889634f * x));
}
__device__ __forceinline__ float fast_tanh(float x) {
    return 1.0f - 2.0f * __builtin_amdgcn_rcpf(1.0f + __builtin_amdgcn_exp2f(2.885390081777927f * x));
}
__device__ __forceinline__ unsigned int pk2(float lo, float hi) {
    return (unsigned int)f2s(lo) | ((unsigned int)f2s(hi) << 16);
}
__device__ __forceinline__ f32x4 up4(uint2 u) {
    return (f32x4){ s2f((unsigned short)u.x), s2f((unsigned short)(u.x >> 16)),
                    s2f((unsigned short)u.y), s2f((unsigned short)(u.y >> 16)) };
}
union H8U4 { half8 h; uint4 u; };
__device__ __forceinline__ half8 ldg_h8(const unsigned short* p) {
    H8U4 t; t.u = *reinterpret_cast<const uint4*>(p); return t.h;
}
__device__ __forceinline__ half8 pack8(float4 a, float4 b) {
    half8 r;
    r[0] = (_Float16)a.x; r[1] = (_Float16)a.y; r[2] = (_Float16)a.z; r[3] = (_Float16)a.w;
    r[4] = (_Float16)b.x; r[5] = (_Float16)b.y; r[6] = (_Float16)b.z; r[7] = (_Float16)b.w;
    return r;
}

// ---------------- pack weights to fp16 ----------------
__global__ void pack_w_kernel(const float* __restrict__ whr, const float* __restrict__ whz,
                              const float* __restrict__ wh,  const float* __restrict__ wxr,
                              const float* __restrict__ wxz, const float* __restrict__ wxn,
                              unsigned short* __restrict__ Wall) {
    const int i = blockIdx.x * 256 + threadIdx.x;  // 0 .. 294911
    float v;
    if (i < 196608) {
        const int m = i >> 16;
        const int r = i & 65535;
        v = (m == 0 ? whr : (m == 1 ? whz : wh))[r];
    } else {
        const int ii = i - 196608;
        const int m = ii >> 15;
        const int r = ii & 32767;
        v = (m == 0 ? wxr : (m == 1 ? wxz : wxn))[r];
    }
    Wall[i] = f2s(v);
}

// ---------------- input projections (weights register-resident, 32 t per block) ----
// grid: 16 btile x (Tc/TPB) tchunks; 512 threads; wave w owns ntiles {2w, 2w+1}.
__global__ __launch_bounds__(512, 1) void proj_kernel(
    const float* __restrict__ x, const unsigned short* __restrict__ Wxp,
    const float* __restrict__ br, const float* __restrict__ bz, const float* __restrict__ bn,
    unsigned short* __restrict__ P, int t0, int TPB) {
    const int tid = threadIdx.x;
    const int w   = tid >> 6;
    const int lane = tid & 63;
    const int l15 = lane & 15;
    const int lq  = lane >> 4;
    const int btile = blockIdx.x & 15;
    const int tc    = blockIdx.x >> 4;
    const int b0 = btile * 16;

    // weight A-fragments: row = w*32 + ntl*16 + l15, k = kt*32 + 8*lq
    half8 wf[3][4][2];
#pragma unroll
    for (int g = 0; g < 3; ++g)
#pragma unroll
        for (int kt = 0; kt < 4; ++kt)
#pragma unroll
            for (int ntl = 0; ntl < 2; ++ntl)
                wf[g][kt][ntl] = ldg_h8(Wxp + g * 32768 + (w * 32 + ntl * 16 + l15) * 128 + kt * 32 + 8 * lq);

    const float* bptr[3] = {br, bz, bn};
    float4 bv[3][2];
#pragma unroll
    for (int g = 0; g < 3; ++g)
#pragma unroll
        for (int ntl = 0; ntl < 2; ++ntl)
            bv[g][ntl] = *reinterpret_cast<const float4*>(bptr[g] + (2 * w + ntl) * 16 + 4 * lq);

    for (int i = 0; i < TPB; ++i) {
        const int tl = tc * TPB + i;           // chunk-relative t
        const int t  = t0 + tl;                // absolute t
        half8 xf[4];
#pragma unroll
        for (int kt = 0; kt < 4; ++kt) {
            const float* xp = x + (size_t)(b0 + l15) * 65536 + t * 128 + kt * 32 + 8 * lq;
            float4 f0 = *reinterpret_cast<const float4*>(xp);
            float4 f1 = *reinterpret_cast<const float4*>(xp + 4);
            xf[kt] = pack8(f0, f1);
        }
        unsigned short* Pb = P + (size_t)tl * 196608 + btile * 12288;
#pragma unroll
        for (int g = 0; g < 3; ++g) {
#pragma unroll
            for (int ntl = 0; ntl < 2; ++ntl) {
                f32x4 acc = {0.f, 0.f, 0.f, 0.f};
#pragma unroll
                for (int kt = 0; kt < 4; ++kt)
                    acc = __builtin_amdgcn_mfma_f32_16x16x32_f16(wf[g][kt][ntl], xf[kt], acc, 0, 0, 0);
                uint2 o;
                o.x = pk2(acc[0] + bv[g][ntl].x, acc[1] + bv[g][ntl].y);
                o.y = pk2(acc[2] + bv[g][ntl].z, acc[3] + bv[g][ntl].w);
                *reinterpret_cast<uint2*>(Pb + (2 * w + ntl) * 768 + g * 256 + lane * 4) = o;
            }
        }
    }
}

// ---------------- recurrent scan (persistent, weights in registers) ----------------
__global__ __launch_bounds__(512, 1) void rec_kernel(
    const unsigned short* __restrict__ Wp, const unsigned short* __restrict__ P,
    float* __restrict__ h_state, int t0, int Tc) {
    const int tid = threadIdx.x;
    const int w = tid >> 6;       // wave 0..7, owns n-cols w*32 .. w*32+31 of each gate
    const int lane = tid & 63;
    const int l15 = lane & 15;    // batch row within tile (and weight n-row for A-frags)
    const int lq = lane >> 4;
    const int btile = blockIdx.x;
    const int b0 = btile * 16;

    // bytes [0,8192): h  (16 rows x 256 n fp16, chunk-XOR swizzled); [8192,16384): rh
    __shared__ __align__(16) unsigned short hl[8192];
    char* lds = reinterpret_cast<char*>(hl);

    // A-fragments of weights: lane l15 = n-row (within 16-tile), k = kt*32 + 8*lq
    half8 wr[8][2], wz[8][2], wn[8][2];
#pragma unroll
    for (int kt = 0; kt < 8; ++kt) {
#pragma unroll
        for (int nt = 0; nt < 2; ++nt) {
            const int row = w * 32 + nt * 16 + l15;
            const int co = kt * 32 + 8 * lq;
            wr[kt][nt] = ldg_h8(Wp + row * 256 + co);
            wz[kt][nt] = ldg_h8(Wp + 65536 + row * 256 + co);
            wn[kt][nt] = ldg_h8(Wp + 131072 + row * 256 + co);
        }
    }

    // loop-invariant LDS addresses (bytes). Row b (512 B) x 32 chunks of 16 B,
    // physical chunk = logical chunk ^ (b & 7).
    const int b7 = l15 & 7;
    int rdaddr[8];
#pragma unroll
    for (int kt = 0; kt < 8; ++kt)
        rdaddr[kt] = l15 * 512 + (((4 * kt + lq) ^ b7) << 4);
    int waddr[2];
#pragma unroll
    for (int nt = 0; nt < 2; ++nt) {
        const int c = 4 * w + 2 * nt + (lq >> 1);
        waddr[nt] = l15 * 512 + ((c ^ b7) << 4) + 8 * (lq & 1);
    }

    // h register state: hreg[nt][j] = h[b = l15][n = w*32 + nt*16 + 4*lq + j]
    float hreg[2][4];
    if (t0 == 0) {
#pragma unroll
        for (int nt = 0; nt < 2; ++nt)
#pragma unroll
            for (int j = 0; j < 4; ++j) hreg[nt][j] = 0.f;
    } else {
#pragma unroll
        for (int nt = 0; nt < 2; ++nt) {
            float4 v = *reinterpret_cast<const float4*>(
                h_state + (b0 + l15) * 256 + w * 32 + nt * 16 + 4 * lq);
            hreg[nt][0] = v.x; hreg[nt][1] = v.y; hreg[nt][2] = v.z; hreg[nt][3] = v.w;
        }
    }
#pragma unroll
    for (int nt = 0; nt < 2; ++nt) {
        uint2 o;
        o.x = pk2(hreg[nt][0], hreg[nt][1]);
        o.y = pk2(hreg[nt][2], hreg[nt][3]);
        *reinterpret_cast<uint2*>(lds + waddr[nt]) = o;
    }
    BARRIER();

    const unsigned short* Pw = P + btile * 12288 + (2 * w) * 768 + lane * 4;
    uint2 cp[3][2], np[3][2];
#pragma unroll
    for (int g = 0; g < 3; ++g)
#pragma unroll
        for (int nt = 0; nt < 2; ++nt)
            cp[g][nt] = *reinterpret_cast<const uint2*>(Pw + nt * 768 + g * 256);

    for (int tl = 0; tl < Tc; ++tl) {
        // prefetch next step's P (stays in flight across raw barriers)
        const unsigned short* Pn = Pw + (size_t)((tl + 1 < Tc) ? tl + 1 : tl) * 196608;
#pragma unroll
        for (int g = 0; g < 3; ++g)
#pragma unroll
            for (int nt = 0; nt < 2; ++nt)
                np[g][nt] = *reinterpret_cast<const uint2*>(Pn + nt * 768 + g * 256);

        // ---- phase A: R and Z MFMAs; epilogue = r-sigmoids only ----
        f32x4 aR[2], aZ[2];
        aR[0] = up4(cp[0][0]);
        aR[1] = up4(cp[0][1]);
        aZ[0] = up4(cp[1][0]);
        aZ[1] = up4(cp[1][1]);
#pragma unroll
        for (int kt = 0; kt < 8; ++kt) {
            half8 a = *reinterpret_cast<const half8*>(lds + rdaddr[kt]);
            aR[0] = __builtin_amdgcn_mfma_f32_16x16x32_f16(wr[kt][0], a, aR[0], 0, 0, 0);
            aR[1] = __builtin_amdgcn_mfma_f32_16x16x32_f16(wr[kt][1], a, aR[1], 0, 0, 0);
            aZ[0] = __builtin_amdgcn_mfma_f32_16x16x32_f16(wz[kt][0], a, aZ[0], 0, 0, 0);
            aZ[1] = __builtin_amdgcn_mfma_f32_16x16x32_f16(wz[kt][1], a, aZ[1], 0, 0, 0);
        }
#pragma unroll
        for (int nt = 0; nt < 2; ++nt) {
            const float r0 = fast_sigmoid(aR[nt][0]);
            const float r1 = fast_sigmoid(aR[nt][1]);
            const float r2 = fast_sigmoid(aR[nt][2]);
            const float r3 = fast_sigmoid(aR[nt][3]);
            uint2 o;
            o.x = pk2(r0 * hreg[nt][0], r1 * hreg[nt][1]);
            o.y = pk2(r2 * hreg[nt][2], r3 * hreg[nt][3]);
            *reinterpret_cast<uint2*>(lds + 8192 + waddr[nt]) = o;
        }
        BARRIER();

        // ---- phase B: z-sigmoids first (trans unit runs during rh ds_reads), then N ----
        float zv[2][4];
#pragma unroll
        for (int nt = 0; nt < 2; ++nt) {
            zv[nt][0] = fast_sigmoid(aZ[nt][0]);
            zv[nt][1] = fast_sigmoid(aZ[nt][1]);
            zv[nt][2] = fast_sigmoid(aZ[nt][2]);
            zv[nt][3] = fast_sigmoid(aZ[nt][3]);
        }
        f32x4 aN[2];
        aN[0] = up4(cp[2][0]);
        aN[1] = up4(cp[2][1]);
#pragma unroll
        for (int kt = 0; kt < 8; ++kt) {
            half8 rf = *reinterpret_cast<const half8*>(lds + 8192 + rdaddr[kt]);
            aN[0] = __builtin_amdgcn_mfma_f32_16x16x32_f16(wn[kt][0], rf, aN[0], 0, 0, 0);
            aN[1] = __builtin_amdgcn_mfma_f32_16x16x32_f16(wn[kt][1], rf, aN[1], 0, 0, 0);
        }
#pragma unroll
        for (int nt = 0; nt < 2; ++nt) {
            const float t0_ = fast_tanh(aN[nt][0]);
            const float t1_ = fast_tanh(aN[nt][1]);
            const float t2_ = fast_tanh(aN[nt][2]);
            const float t3_ = fast_tanh(aN[nt][3]);
            hreg[nt][0] = t0_ + zv[nt][0] * (hreg[nt][0] - t0_);
            hreg[nt][1] = t1_ + zv[nt][1] * (hreg[nt][1] - t1_);
            hreg[nt][2] = t2_ + zv[nt][2] * (hreg[nt][2] - t2_);
            hreg[nt][3] = t3_ + zv[nt][3] * (hreg[nt][3] - t3_);
            uint2 o;
            o.x = pk2(hreg[nt][0], hreg[nt][1]);
            o.y = pk2(hreg[nt][2], hreg[nt][3]);
            *reinterpret_cast<uint2*>(lds + waddr[nt]) = o;
        }
        BARRIER();

#pragma unroll
        for (int g = 0; g < 3; ++g)
#pragma unroll
            for (int nt = 0; nt < 2; ++nt)
                cp[g][nt] = np[g][nt];
    }

#pragma unroll
    for (int nt = 0; nt < 2; ++nt) {
        float4 st;
        st.x = hreg[nt][0]; st.y = hreg[nt][1]; st.z = hreg[nt][2]; st.w = hreg[nt][3];
        *reinterpret_cast<float4*>(h_state + (b0 + l15) * 256 + w * 32 + nt * 16 + 4 * lq) = st;
    }
}

// ---------------- MLP head + softmax ----------------
__global__ __launch_bounds__(64) void head_kernel(
    const float* __restrict__ h_state, const float* __restrict__ w1, const float* __restrict__ b1,
    const float* __restrict__ w2, const float* __restrict__ b2, float* __restrict__ out) {
    const int row = blockIdx.x;
    const int lane = threadIdx.x;
    __shared__ float hs[256];
    __shared__ float h2[64];
    __shared__ float lg[10];
    float4 v = *reinterpret_cast<const float4*>(h_state + row * 256 + lane * 4);
    hs[lane * 4 + 0] = fast_sigmoid(v.x);
    hs[lane * 4 + 1] = fast_sigmoid(v.y);
    hs[lane * 4 + 2] = fast_sigmoid(v.z);
    hs[lane * 4 + 3] = fast_sigmoid(v.w);
    __syncthreads();
    float acc = b1[lane];
#pragma unroll 4
    for (int k = 0; k < 256; k += 4) {
        float4 wv = *reinterpret_cast<const float4*>(w1 + lane * 256 + k);
        acc += hs[k] * wv.x + hs[k + 1] * wv.y + hs[k + 2] * wv.z + hs[k + 3] * wv.w;
    }
    h2[lane] = fast_sigmoid(acc);
    __syncthreads();
    if (lane < 10) {
        float a2 = b2[lane];
        for (int k = 0; k < 64; ++k) a2 += h2[k] * w2[lane * 64 + k];
        lg[lane] = a2;
    }
    __syncthreads();
    if (lane < 10) {
        float m = lg[0];
#pragma unroll
        for (int k = 1; k < 10; ++k) m = fmaxf(m, lg[k]);
        float s = 0.f;
#pragma unroll
        for (int k = 0; k < 10; ++k) s += __expf(lg[k] - m);
        out[row * 10 + lane] = __expf(lg[lane] - m) / s;
    }
}

extern "C" void kernel_launch(void* const* d_in, const int* in_sizes, int n_in,
                              void* d_out, int out_size, void* d_ws, size_t ws_size,
                              hipStream_t stream) {
    const float* x   = (const float*)d_in[0];
    const float* wxr = (const float*)d_in[1];
    const float* whr = (const float*)d_in[2];
    const float* br  = (const float*)d_in[3];
    const float* wxz = (const float*)d_in[4];
    const float* whz = (const float*)d_in[5];
    const float* bz  = (const float*)d_in[6];
    const float* wxn = (const float*)d_in[7];
    const float* wh  = (const float*)d_in[8];
    const float* bn  = (const float*)d_in[9];
    const float* w1  = (const float*)d_in[10];
    const float* b1  = (const float*)d_in[11];
    const float* w2  = (const float*)d_in[12];
    const float* b2  = (const float*)d_in[13];
    float* out = (float*)d_out;

    char* ws = (char*)d_ws;
    unsigned short* Wp  = (unsigned short*)ws;
    unsigned short* Wxp = (unsigned short*)(ws + 393216);
    float* h_state = (float*)(ws + 589824);
    unsigned short* P = (unsigned short*)(ws + 851968);
    const size_t avail = (ws_size > 851968) ? ws_size - 851968 : 0;
    int Tc = 512;
    while (Tc > 1 && (size_t)Tc * 393216 > avail) Tc >>= 1;
    const int TPB = Tc < 32 ? Tc : 32;

    pack_w_kernel<<<dim3(1152), 256, 0, stream>>>(whr, whz, wh, wxr, wxz, wxn, Wp);
    for (int t0 = 0; t0 < 512; t0 += Tc) {
        proj_kernel<<<dim3(16 * (Tc / TPB)), 512, 0, stream>>>(x, Wxp, br, bz, bn, P, t0, TPB);
        rec_kernel<<<dim3(16), 512, 0, stream>>>(Wp, P, h_state, t0, Tc);
    }
    head_kernel<<<dim3(256), 64, 0, stream>>>(h_state, w1, b1, w2, b2, out);
}